// Round 14
// baseline (781.975 us; speedup 1.0000x reference)
//
#include <hip/hip_runtime.h>
#include <hip/hip_bf16.h>
#include <hip/hip_cooperative_groups.h>
#include <math.h>

// ---------------------------------------------------------------------------
// 3-layer GAT (PyG GATConv semantics, self-loops, eval mode).
// Round-14 (= round-6..13 resubmission; never yet run on HW due to repeated
// GPU acquisition timeouts): ONE cooperative kernel (8 grid syncs) replaces
// 15 dispatches — round-5 evidence shows ~6-9 us per-dispatch overhead
// dominates. Per layer, msum+agg+proj are fused: alpha staged in LDS
// (DCAP=96, safe recompute fallback), AGG rows staged in LDS, W2 projection
// node-blocked 8-wide per block. Falls back to the proven round-5
// multi-dispatch path if cooperative launch is rejected.
// ---------------------------------------------------------------------------

#define NEG_SLOPE 0.2f
#define DCAP 96

namespace cg = cooperative_groups;

__device__ __forceinline__ float lrelu(float v) {
  return v > 0.f ? v : NEG_SLOPE * v;
}

// ---------------- cooperative mega-kernel ----------------

struct CoopP {
  const float* x; const int* ei;
  const float* W1; const float* as1; const float* ad1; const float* b1;
  const float* W2; const float* as2; const float* ad2; const float* b2;
  const float* W3; const float* as3; const float* ad3; const float* b3;
  float* outf;
  int n, E;
  int* deg; int* rowptr; int* cursor; int* esrc;
  float* als; float* ald; float* selfe; float* av;
  float* x1; float* x2; float* h3;
};

template <int K>
__device__ __forceinline__ void logits_one(const float* __restrict__ X,
                                           const float* __restrict__ avs,
                                           const float* __restrict__ avd,
                                           float* __restrict__ als,
                                           float* __restrict__ ald,
                                           float* __restrict__ selfe, int idx) {
  int node = idx >> 3;
  int h = idx & 7;
  const float* xr = X + (size_t)node * K;
  const float* vs = avs + h * K;
  const float* vd = avd + h * K;
  float s0 = 0.f, s1 = 0.f;
#pragma unroll
  for (int k4 = 0; k4 < K / 4; ++k4) {
    float4 xv = *reinterpret_cast<const float4*>(&xr[k4 * 4]);
    float4 a = *reinterpret_cast<const float4*>(&vs[k4 * 4]);
    float4 b = *reinterpret_cast<const float4*>(&vd[k4 * 4]);
    s0 += xv.x * a.x + xv.y * a.y + xv.z * a.z + xv.w * a.w;
    s1 += xv.x * b.x + xv.y * b.y + xv.z * b.z + xv.w * b.w;
  }
  als[idx] = s0;
  ald[idx] = s1;
  selfe[idx] = lrelu(s0 + s1);
}

__global__ __launch_bounds__(256, 4) void gat_coop(CoopP P) {
  cg::grid_group grid = cg::this_grid();
  const int t = threadIdx.x;
  const int lane = t & 63;
  const int w = t >> 6;
  const int bid = blockIdx.x;
  const int nb = gridDim.x;
  const int tid = bid * 256 + t;
  const int nthr = nb * 256;
  const int wid = bid * 4 + w;
  const int nwv = nb * 4;
  const int n = P.n, E = P.E;

  __shared__ __align__(16) float s_alpha[4][DCAP * 8];  // per-wave alpha stage
  __shared__ __align__(16) float s_AGG[8][512];         // AGG rows (L1 uses [w][0..255])
  __shared__ float s_sel[4][8], s_m[4][8], s_rs[4][8];
  __shared__ int s_scan[256];

  // ---- P0: zero deg ----
  for (int i = tid; i < n; i += nthr) P.deg[i] = 0;
  grid.sync();

  // ---- P1: count degrees ----
  for (int e = tid; e < E; e += nthr) atomicAdd(&P.deg[P.ei[E + e]], 1);
  grid.sync();

  // ---- P2: scan (block 0) + prep_av (blocks 1,2) ----
  if (bid == 0) {
    int chunk = (n + 255) >> 8;
    int lo = t * chunk;
    int hi = min(lo + chunk, n);
    int s = 0;
    for (int i = lo; i < hi; ++i) s += P.deg[i];
    s_scan[t] = s;
    __syncthreads();
    for (int off = 1; off < 256; off <<= 1) {
      int v = (t >= off) ? s_scan[t - off] : 0;
      __syncthreads();
      s_scan[t] += v;
      __syncthreads();
    }
    int run = (t == 0) ? 0 : s_scan[t - 1];
    for (int i = lo; i < hi; ++i) {
      P.rowptr[i] = run;
      P.cursor[i] = run;
      run += P.deg[i];
    }
    if (t == 255) P.rowptr[n] = s_scan[255];
  } else if (bid == 1) {
    // av1: [0..256)=src, [256..512)=dst  (h in 0..7, k in 0..31)
    int h = t >> 5, k = t & 31;
    float s = 0.f, d = 0.f;
#pragma unroll
    for (int c = 0; c < 8; ++c) {
      float wv = P.W1[k * 64 + h * 8 + c];
      s += wv * P.as1[h * 8 + c];
      d += wv * P.ad1[h * 8 + c];
    }
    P.av[t] = s;
    P.av[256 + t] = d;
  } else if (bid == 2) {
    // av2: [512..1024)=src, [1024..1536)=dst  (h in 0..7, k in 0..63)
    for (int idx = t; idx < 512; idx += 256) {
      int h = idx >> 6, k = idx & 63;
      float s = 0.f, d = 0.f;
#pragma unroll
      for (int c = 0; c < 64; ++c) {
        float wv = P.W2[(size_t)k * 512 + h * 64 + c];
        s += wv * P.as2[h * 64 + c];
        d += wv * P.ad2[h * 64 + c];
      }
      P.av[512 + idx] = s;
      P.av[1024 + idx] = d;
    }
  }
  grid.sync();

  // ---- P3: fill edges + layer-1 logits ----
  for (int e = tid; e < E; e += nthr) {
    int d = P.ei[E + e];
    int pos = atomicAdd(&P.cursor[d], 1);
    P.esrc[pos] = P.ei[e];
  }
  for (int idx = tid; idx < n * 8; idx += nthr)
    logits_one<32>(P.x, P.av, P.av + 256, P.als, P.ald, P.selfe, idx);
  grid.sync();

  // ---- P4: fused layer 1 (msum + agg + proj) -> x1 ----
  for (int nd = wid; nd < n; nd += nwv) {
    int r0 = P.rowptr[nd], r1 = P.rowptr[nd + 1];
    // A: per-(slot,head) softmax stats
    int i = lane >> 3, h = lane & 7;
    float aldv = P.ald[nd * 8 + h];
    float e0 = P.selfe[nd * 8 + h];
    float m = e0;
    for (int p = r0 + i; p < r1; p += 8)
      m = fmaxf(m, lrelu(P.als[P.esrc[p] * 8 + h] + aldv));
    m = fmaxf(m, __shfl_xor(m, 8, 64));
    m = fmaxf(m, __shfl_xor(m, 16, 64));
    m = fmaxf(m, __shfl_xor(m, 32, 64));
    float s = 0.f;
    for (int p = r0 + i; p < r1; p += 8)
      s += __expf(lrelu(P.als[P.esrc[p] * 8 + h] + aldv) - m);
    s += __shfl_xor(s, 8, 64);
    s += __shfl_xor(s, 16, 64);
    s += __shfl_xor(s, 32, 64);
    float a0 = __expf(e0 - m);
    float rs = 1.f / (s + a0 + 1e-16f);
    if (i == 0) {
      s_sel[w][h] = a0 * rs;
      s_m[w][h] = m;
      s_rs[w][h] = rs;
    }
    for (int p = r0 + i; p < r1; p += 8) {
      int o = p - r0;
      if (o < DCAP)
        s_alpha[w][o * 8 + h] = __expf(lrelu(P.als[P.esrc[p] * 8 + h] + aldv) - m) * rs;
    }
    // B: aggregate x rows (ch = lane&31, edge slot = lane>>5)
    int ch = lane & 31, es = lane >> 5;
    float acc[8];
    {
      float xs = (es == 0) ? P.x[(size_t)nd * 32 + ch] : 0.f;
#pragma unroll
      for (int q = 0; q < 8; ++q) acc[q] = s_sel[w][q] * xs;
    }
    for (int p = r0 + es; p < r1; p += 2) {
      int src = P.esrc[p];
      float xv = P.x[(size_t)src * 32 + ch];
      int o = p - r0;
      if (o < DCAP) {
        const float4* ap = reinterpret_cast<const float4*>(&s_alpha[w][o * 8]);
        float4 av0 = ap[0], av1 = ap[1];
        acc[0] += av0.x * xv; acc[1] += av0.y * xv;
        acc[2] += av0.z * xv; acc[3] += av0.w * xv;
        acc[4] += av1.x * xv; acc[5] += av1.y * xv;
        acc[6] += av1.z * xv; acc[7] += av1.w * xv;
      } else {  // safety fallback (never triggers for this graph)
#pragma unroll
        for (int q = 0; q < 8; ++q) {
          float ev = lrelu(P.als[src * 8 + q] + P.ald[nd * 8 + q]);
          acc[q] += __expf(ev - s_m[w][q]) * s_rs[w][q] * xv;
        }
      }
    }
#pragma unroll
    for (int q = 0; q < 8; ++q) acc[q] += __shfl_xor(acc[q], 32, 64);
    if (es == 0) {
#pragma unroll
      for (int q = 0; q < 8; ++q) s_AGG[w][q * 32 + ch] = acc[q];
    }
    // proj: out col = lane
    int col = lane, hc = col >> 3;
    float pa = 0.f;
    for (int k = 0; k < 32; ++k)
      pa += s_AGG[w][hc * 32 + k] * P.W1[k * 64 + col];
    float v = pa + P.b1[col];
    v = v > 0.f ? v : expm1f(v);
    P.x1[(size_t)nd * 64 + col] = v;
  }
  grid.sync();

  // ---- P5: layer-2 logits ----
  for (int idx = tid; idx < n * 8; idx += nthr)
    logits_one<64>(P.x1, P.av + 512, P.av + 1024, P.als, P.ald, P.selfe, idx);
  grid.sync();

  // ---- P6: fused layer 2 (msum + agg + block-proj) -> x2 ----
  int ngrp = (n + 7) >> 3;
  for (int g = bid; g < ngrp; g += nb) {
    for (int j = 0; j < 2; ++j) {
      int nd = g * 8 + w * 2 + j;
      if (nd < n) {
        int r0 = P.rowptr[nd], r1 = P.rowptr[nd + 1];
        int i = lane >> 3, h = lane & 7;
        float aldv = P.ald[nd * 8 + h];
        float e0 = P.selfe[nd * 8 + h];
        float m = e0;
        for (int p = r0 + i; p < r1; p += 8)
          m = fmaxf(m, lrelu(P.als[P.esrc[p] * 8 + h] + aldv));
        m = fmaxf(m, __shfl_xor(m, 8, 64));
        m = fmaxf(m, __shfl_xor(m, 16, 64));
        m = fmaxf(m, __shfl_xor(m, 32, 64));
        float s = 0.f;
        for (int p = r0 + i; p < r1; p += 8)
          s += __expf(lrelu(P.als[P.esrc[p] * 8 + h] + aldv) - m);
        s += __shfl_xor(s, 8, 64);
        s += __shfl_xor(s, 16, 64);
        s += __shfl_xor(s, 32, 64);
        float a0 = __expf(e0 - m);
        float rs = 1.f / (s + a0 + 1e-16f);
        if (i == 0) {
          s_sel[w][h] = a0 * rs;
          s_m[w][h] = m;
          s_rs[w][h] = rs;
        }
        for (int p = r0 + i; p < r1; p += 8) {
          int o = p - r0;
          if (o < DCAP)
            s_alpha[w][o * 8 + h] = __expf(lrelu(P.als[P.esrc[p] * 8 + h] + aldv) - m) * rs;
        }
        // B: aggregate x1 rows, lane = channel (64)
        float acc[8];
        float xs = P.x1[(size_t)nd * 64 + lane];
#pragma unroll
        for (int q = 0; q < 8; ++q) acc[q] = s_sel[w][q] * xs;
        int p = r0;
        for (; p + 2 <= r1; p += 2) {
          int s0i = P.esrc[p], s1i = P.esrc[p + 1];
          float xv0 = P.x1[(size_t)s0i * 64 + lane];
          float xv1 = P.x1[(size_t)s1i * 64 + lane];
          int o0 = p - r0, o1 = o0 + 1;
          if (o1 < DCAP) {
            const float4* a0p = reinterpret_cast<const float4*>(&s_alpha[w][o0 * 8]);
            const float4* a1p = reinterpret_cast<const float4*>(&s_alpha[w][o1 * 8]);
            float4 a00 = a0p[0], a01 = a0p[1], a10 = a1p[0], a11 = a1p[1];
            acc[0] += a00.x * xv0; acc[1] += a00.y * xv0;
            acc[2] += a00.z * xv0; acc[3] += a00.w * xv0;
            acc[4] += a01.x * xv0; acc[5] += a01.y * xv0;
            acc[6] += a01.z * xv0; acc[7] += a01.w * xv0;
            acc[0] += a10.x * xv1; acc[1] += a10.y * xv1;
            acc[2] += a10.z * xv1; acc[3] += a10.w * xv1;
            acc[4] += a11.x * xv1; acc[5] += a11.y * xv1;
            acc[6] += a11.z * xv1; acc[7] += a11.w * xv1;
          } else {
#pragma unroll
            for (int q = 0; q < 8; ++q) {
              float ev0 = lrelu(P.als[s0i * 8 + q] + P.ald[nd * 8 + q]);
              float ev1 = lrelu(P.als[s1i * 8 + q] + P.ald[nd * 8 + q]);
              acc[q] += __expf(ev0 - s_m[w][q]) * s_rs[w][q] * xv0;
              acc[q] += __expf(ev1 - s_m[w][q]) * s_rs[w][q] * xv1;
            }
          }
        }
        if (p < r1) {
          int s0i = P.esrc[p];
          float xv0 = P.x1[(size_t)s0i * 64 + lane];
          int o0 = p - r0;
          if (o0 < DCAP) {
            const float4* a0p = reinterpret_cast<const float4*>(&s_alpha[w][o0 * 8]);
            float4 a00 = a0p[0], a01 = a0p[1];
            acc[0] += a00.x * xv0; acc[1] += a00.y * xv0;
            acc[2] += a00.z * xv0; acc[3] += a00.w * xv0;
            acc[4] += a01.x * xv0; acc[5] += a01.y * xv0;
            acc[6] += a01.z * xv0; acc[7] += a01.w * xv0;
          } else {
#pragma unroll
            for (int q = 0; q < 8; ++q) {
              float ev0 = lrelu(P.als[s0i * 8 + q] + P.ald[nd * 8 + q]);
              acc[q] += __expf(ev0 - s_m[w][q]) * s_rs[w][q] * xv0;
            }
          }
        }
#pragma unroll
        for (int q = 0; q < 8; ++q) s_AGG[w * 2 + j][q * 64 + lane] = acc[q];
      }
    }
    __syncthreads();
    // block proj: thread t -> cols (lane)*8..+7 for nodes {g*8+2w, g*8+2w+1}
    {
      int cg_ = lane, jg = w;
      int c0 = cg_ * 8, hc = cg_ >> 3;
      int n0 = g * 8 + jg * 2;
      float pa[2][8];
#pragma unroll
      for (int jj = 0; jj < 2; ++jj)
#pragma unroll
        for (int c = 0; c < 8; ++c) pa[jj][c] = 0.f;
      for (int k = 0; k < 64; ++k) {
        float4 w0 = *reinterpret_cast<const float4*>(&P.W2[(size_t)k * 512 + c0]);
        float4 w1 = *reinterpret_cast<const float4*>(&P.W2[(size_t)k * 512 + c0 + 4]);
        float xa = s_AGG[jg * 2][hc * 64 + k];
        float xb = s_AGG[jg * 2 + 1][hc * 64 + k];
        pa[0][0] += xa * w0.x; pa[0][1] += xa * w0.y;
        pa[0][2] += xa * w0.z; pa[0][3] += xa * w0.w;
        pa[0][4] += xa * w1.x; pa[0][5] += xa * w1.y;
        pa[0][6] += xa * w1.z; pa[0][7] += xa * w1.w;
        pa[1][0] += xb * w0.x; pa[1][1] += xb * w0.y;
        pa[1][2] += xb * w0.z; pa[1][3] += xb * w0.w;
        pa[1][4] += xb * w1.x; pa[1][5] += xb * w1.y;
        pa[1][6] += xb * w1.z; pa[1][7] += xb * w1.w;
      }
      float4 bv0 = *reinterpret_cast<const float4*>(&P.b2[c0]);
      float4 bv1 = *reinterpret_cast<const float4*>(&P.b2[c0 + 4]);
#pragma unroll
      for (int jj = 0; jj < 2; ++jj) {
        int nd = n0 + jj;
        if (nd < n) {
          float vv[8];
          vv[0] = pa[jj][0] + bv0.x; vv[1] = pa[jj][1] + bv0.y;
          vv[2] = pa[jj][2] + bv0.z; vv[3] = pa[jj][3] + bv0.w;
          vv[4] = pa[jj][4] + bv1.x; vv[5] = pa[jj][5] + bv1.y;
          vv[6] = pa[jj][6] + bv1.z; vv[7] = pa[jj][7] + bv1.w;
#pragma unroll
          for (int c = 0; c < 8; ++c) vv[c] = vv[c] > 0.f ? vv[c] : expm1f(vv[c]);
          float4* o = reinterpret_cast<float4*>(&P.x2[(size_t)nd * 512 + c0]);
          o[0] = make_float4(vv[0], vv[1], vv[2], vv[3]);
          o[1] = make_float4(vv[4], vv[5], vv[6], vv[7]);
        }
      }
    }
    __syncthreads();
  }
  grid.sync();

  // ---- P7: layer-3 GEMM (512->6) + logits ----
  for (int nd = wid; nd < n; nd += nwv) {
    float a6[6] = {0.f, 0.f, 0.f, 0.f, 0.f, 0.f};
    for (int k = lane; k < 512; k += 64) {
      float xv = P.x2[(size_t)nd * 512 + k];
#pragma unroll
      for (int c = 0; c < 6; ++c) a6[c] += xv * P.W3[k * 6 + c];
    }
#pragma unroll
    for (int c = 0; c < 6; ++c) {
#pragma unroll
      for (int off = 32; off >= 1; off >>= 1)
        a6[c] += __shfl_down(a6[c], off, 64);
    }
    if (lane == 0) {
      float s0 = 0.f, s1 = 0.f;
#pragma unroll
      for (int c = 0; c < 6; ++c) {
        P.h3[(size_t)nd * 6 + c] = a6[c];
        s0 += a6[c] * P.as3[c];
        s1 += a6[c] * P.ad3[c];
      }
      P.als[nd] = s0;
      P.ald[nd] = s1;
      P.selfe[nd] = lrelu(s0 + s1);
    }
  }
  grid.sync();

  // ---- P8: fused layer-3 softmax + aggregate -> out ----
  for (int nd = wid; nd < n; nd += nwv) {
    int r0 = P.rowptr[nd], r1 = P.rowptr[nd + 1];
    float aldv = P.ald[nd];
    float e0 = P.selfe[nd];
    float m = e0;
    for (int p = r0 + lane; p < r1; p += 64)
      m = fmaxf(m, lrelu(P.als[P.esrc[p]] + aldv));
#pragma unroll
    for (int off = 1; off < 64; off <<= 1) m = fmaxf(m, __shfl_xor(m, off, 64));
    float s = 0.f;
    for (int p = r0 + lane; p < r1; p += 64)
      s += __expf(lrelu(P.als[P.esrc[p]] + aldv) - m);
#pragma unroll
    for (int off = 1; off < 64; off <<= 1) s += __shfl_xor(s, off, 64);
    float a0 = __expf(e0 - m);
    float rs = 1.f / (s + a0 + 1e-16f);
    int ch = lane < 6 ? lane : 0;
    float acc = a0 * rs * P.h3[(size_t)nd * 6 + ch];
    for (int p = r0; p < r1; ++p) {
      int src = P.esrc[p];
      float ev = lrelu(P.als[src] + aldv);
      acc += __expf(ev - m) * rs * P.h3[(size_t)src * 6 + ch];
    }
    if (lane < 6) P.outf[(size_t)nd * 6 + lane] = acc + P.b3[lane];
  }
}

// ===========================================================================
// Fallback path: exact round-5 kernels (proven PASS at 256 us)
// ===========================================================================

__global__ __launch_bounds__(256) void count_deg(const int* __restrict__ ei,
                                                 int* __restrict__ deg, int E) {
  int e = blockIdx.x * blockDim.x + threadIdx.x;
  if (e < E) atomicAdd(&deg[ei[E + e]], 1);
}

__global__ __launch_bounds__(1024) void scan3(const int* __restrict__ deg,
                                              int* __restrict__ rowptr,
                                              int* __restrict__ cursor, int n,
                                              const float* __restrict__ W1,
                                              const float* __restrict__ as1,
                                              const float* __restrict__ ad1,
                                              const float* __restrict__ W2,
                                              const float* __restrict__ as2,
                                              const float* __restrict__ ad2,
                                              float* __restrict__ av) {
  int t = threadIdx.x;
  if (blockIdx.x == 0) {
    __shared__ int part[1024];
    int chunk = (n + 1023) >> 10;
    int lo = t * chunk;
    int hi = min(lo + chunk, n);
    int s = 0;
    for (int i = lo; i < hi; ++i) s += deg[i];
    part[t] = s;
    __syncthreads();
    for (int off = 1; off < 1024; off <<= 1) {
      int v = (t >= off) ? part[t - off] : 0;
      __syncthreads();
      part[t] += v;
      __syncthreads();
    }
    int run = (t == 0) ? 0 : part[t - 1];
    for (int i = lo; i < hi; ++i) {
      rowptr[i] = run;
      cursor[i] = run;
      run += deg[i];
    }
    if (t == 1023) rowptr[n] = part[1023];
  } else if (blockIdx.x == 1) {
    if (t < 256) {
      int h = t >> 5, k = t & 31;
      float s = 0.f, d = 0.f;
#pragma unroll
      for (int c = 0; c < 8; ++c) {
        float wv = W1[k * 64 + h * 8 + c];
        s += wv * as1[h * 8 + c];
        d += wv * ad1[h * 8 + c];
      }
      av[t] = s;
      av[256 + t] = d;
    }
  } else {
    if (t < 512) {
      int h = t >> 6, k = t & 63;
      float s = 0.f, d = 0.f;
#pragma unroll
      for (int c = 0; c < 64; ++c) {
        float wv = W2[(size_t)k * 512 + h * 64 + c];
        s += wv * as2[h * 64 + c];
        d += wv * ad2[h * 64 + c];
      }
      av[512 + t] = s;
      av[1024 + t] = d;
    }
  }
}

__global__ __launch_bounds__(256) void fill_edges(const int* __restrict__ ei,
                                                  int* __restrict__ cursor,
                                                  int* __restrict__ esrc, int E) {
  int e = blockIdx.x * blockDim.x + threadIdx.x;
  if (e < E) {
    int d = ei[E + e];
    int pos = atomicAdd(&cursor[d], 1);
    esrc[pos] = ei[e];
  }
}

template <int HH, int K>
__global__ __launch_bounds__(256) void logits_x(const float* __restrict__ X,
                                                const float* __restrict__ avs,
                                                const float* __restrict__ avd,
                                                float* __restrict__ als,
                                                float* __restrict__ ald,
                                                float* __restrict__ selfe, int n) {
  int idx = blockIdx.x * blockDim.x + threadIdx.x;
  if (idx >= n * HH) return;
  int node = idx / HH;
  int h = idx - node * HH;
  const float* xr = X + (size_t)node * K;
  const float* vs = avs + h * K;
  const float* vd = avd + h * K;
  float s0 = 0.f, s1 = 0.f;
#pragma unroll
  for (int k4 = 0; k4 < K / 4; ++k4) {
    float4 xv = *reinterpret_cast<const float4*>(&xr[k4 * 4]);
    float4 a = *reinterpret_cast<const float4*>(&vs[k4 * 4]);
    float4 b = *reinterpret_cast<const float4*>(&vd[k4 * 4]);
    s0 += xv.x * a.x + xv.y * a.y + xv.z * a.z + xv.w * a.w;
    s1 += xv.x * b.x + xv.y * b.y + xv.z * b.z + xv.w * b.w;
  }
  als[idx] = s0;
  ald[idx] = s1;
  selfe[idx] = lrelu(s0 + s1);
}

__global__ __launch_bounds__(256) void msum_alpha8(const int* __restrict__ esrc,
                                                   const float* __restrict__ als,
                                                   const float* __restrict__ ald,
                                                   const float* __restrict__ selfe,
                                                   const int* __restrict__ rowptr,
                                                   float* __restrict__ alpha,
                                                   float* __restrict__ asel, int n) {
  int node = blockIdx.x * 4 + (threadIdx.x >> 6);
  int lane = threadIdx.x & 63;
  if (node >= n) return;
  int i = lane >> 3;
  int h = lane & 7;
  float aldv = ald[node * 8 + h];
  float e0 = selfe[node * 8 + h];
  int r0 = rowptr[node], r1 = rowptr[node + 1];
  float m = e0;
  for (int p = r0 + i; p < r1; p += 8)
    m = fmaxf(m, lrelu(als[esrc[p] * 8 + h] + aldv));
  m = fmaxf(m, __shfl_xor(m, 8, 64));
  m = fmaxf(m, __shfl_xor(m, 16, 64));
  m = fmaxf(m, __shfl_xor(m, 32, 64));
  float s = 0.f;
  for (int p = r0 + i; p < r1; p += 8)
    s += __expf(lrelu(als[esrc[p] * 8 + h] + aldv) - m);
  s += __shfl_xor(s, 8, 64);
  s += __shfl_xor(s, 16, 64);
  s += __shfl_xor(s, 32, 64);
  float a0 = __expf(e0 - m);
  float rs = 1.f / (s + a0 + 1e-16f);
  if (lane < 8) asel[node * 8 + lane] = a0 * rs;
  for (int p = r0 + i; p < r1; p += 8)
    alpha[(size_t)p * 8 + h] = __expf(lrelu(als[esrc[p] * 8 + h] + aldv) - m) * rs;
}

__global__ __launch_bounds__(256) void msum_alpha1(const int* __restrict__ esrc,
                                                   const float* __restrict__ als,
                                                   const float* __restrict__ ald,
                                                   const float* __restrict__ selfe,
                                                   const int* __restrict__ rowptr,
                                                   float* __restrict__ alpha,
                                                   float* __restrict__ asel, int n) {
  int node = blockIdx.x * 4 + (threadIdx.x >> 6);
  int lane = threadIdx.x & 63;
  if (node >= n) return;
  float aldv = ald[node];
  float e0 = selfe[node];
  int r0 = rowptr[node], r1 = rowptr[node + 1];
  float m = e0;
  for (int p = r0 + lane; p < r1; p += 64)
    m = fmaxf(m, lrelu(als[esrc[p]] + aldv));
#pragma unroll
  for (int off = 1; off < 64; off <<= 1) m = fmaxf(m, __shfl_xor(m, off, 64));
  float s = 0.f;
  for (int p = r0 + lane; p < r1; p += 64)
    s += __expf(lrelu(als[esrc[p]] + aldv) - m);
#pragma unroll
  for (int off = 1; off < 64; off <<= 1) s += __shfl_xor(s, off, 64);
  float a0 = __expf(e0 - m);
  float rs = 1.f / (s + a0 + 1e-16f);
  if (lane == 0) asel[node] = a0 * rs;
  for (int p = r0 + lane; p < r1; p += 64)
    alpha[p] = __expf(lrelu(als[esrc[p]] + aldv) - m) * rs;
}

__global__ __launch_bounds__(256) void agg1(const float* __restrict__ X,
                                            const float* __restrict__ alpha,
                                            const float* __restrict__ asel,
                                            const int* __restrict__ rowptr,
                                            const int* __restrict__ esrc,
                                            float* __restrict__ AGG, int n) {
  int node = blockIdx.x * 4 + (threadIdx.x >> 6);
  int lane = threadIdx.x & 63;
  if (node >= n) return;
  int ch = lane & 31;
  int eslot = lane >> 5;
  float acc[8];
  if (eslot == 0) {
    float xs = X[((unsigned)node << 5) + ch];
#pragma unroll
    for (int h = 0; h < 8; ++h) acc[h] = asel[node * 8 + h] * xs;
  } else {
#pragma unroll
    for (int h = 0; h < 8; ++h) acc[h] = 0.f;
  }
  int r0 = rowptr[node], r1 = rowptr[node + 1];
  int p = r0 + eslot;
  for (; p + 2 < r1; p += 4) {
    int s0 = esrc[p], s1 = esrc[p + 2];
    float xv0 = X[((unsigned)s0 << 5) + ch];
    float xv1 = X[((unsigned)s1 << 5) + ch];
    float4 a00 = *reinterpret_cast<const float4*>(&alpha[(size_t)p * 8]);
    float4 a01 = *reinterpret_cast<const float4*>(&alpha[(size_t)p * 8 + 4]);
    float4 a10 = *reinterpret_cast<const float4*>(&alpha[(size_t)(p + 2) * 8]);
    float4 a11 = *reinterpret_cast<const float4*>(&alpha[(size_t)(p + 2) * 8 + 4]);
    acc[0] += a00.x * xv0; acc[1] += a00.y * xv0;
    acc[2] += a00.z * xv0; acc[3] += a00.w * xv0;
    acc[4] += a01.x * xv0; acc[5] += a01.y * xv0;
    acc[6] += a01.z * xv0; acc[7] += a01.w * xv0;
    acc[0] += a10.x * xv1; acc[1] += a10.y * xv1;
    acc[2] += a10.z * xv1; acc[3] += a10.w * xv1;
    acc[4] += a11.x * xv1; acc[5] += a11.y * xv1;
    acc[6] += a11.z * xv1; acc[7] += a11.w * xv1;
  }
  if (p < r1) {
    int s0 = esrc[p];
    float xv0 = X[((unsigned)s0 << 5) + ch];
    float4 a00 = *reinterpret_cast<const float4*>(&alpha[(size_t)p * 8]);
    float4 a01 = *reinterpret_cast<const float4*>(&alpha[(size_t)p * 8 + 4]);
    acc[0] += a00.x * xv0; acc[1] += a00.y * xv0;
    acc[2] += a00.z * xv0; acc[3] += a00.w * xv0;
    acc[4] += a01.x * xv0; acc[5] += a01.y * xv0;
    acc[6] += a01.z * xv0; acc[7] += a01.w * xv0;
  }
#pragma unroll
  for (int h = 0; h < 8; ++h) acc[h] += __shfl_xor(acc[h], 32, 64);
  if (eslot == 0) {
    unsigned base = (unsigned)node * 256 + ch;
#pragma unroll
    for (int h = 0; h < 8; ++h) AGG[base + h * 32] = acc[h];
  }
}

__global__ __launch_bounds__(256) void agg2(const float* __restrict__ X,
                                            const float* __restrict__ alpha,
                                            const float* __restrict__ asel,
                                            const int* __restrict__ rowptr,
                                            const int* __restrict__ esrc,
                                            float* __restrict__ AGG, int n) {
  int node = blockIdx.x * 4 + (threadIdx.x >> 6);
  int lane = threadIdx.x & 63;
  if (node >= n) return;
  float acc[8];
  float xs = X[((unsigned)node << 6) + lane];
#pragma unroll
  for (int h = 0; h < 8; ++h) acc[h] = asel[node * 8 + h] * xs;
  int r0 = rowptr[node], r1 = rowptr[node + 1];
  int p = r0;
  for (; p + 4 <= r1; p += 4) {
    int s0 = esrc[p], s1 = esrc[p + 1], s2 = esrc[p + 2], s3 = esrc[p + 3];
    float xv0 = X[((unsigned)s0 << 6) + lane];
    float xv1 = X[((unsigned)s1 << 6) + lane];
    float xv2 = X[((unsigned)s2 << 6) + lane];
    float xv3 = X[((unsigned)s3 << 6) + lane];
#pragma unroll
    for (int q = 0; q < 4; ++q) {
      float xv = q == 0 ? xv0 : q == 1 ? xv1 : q == 2 ? xv2 : xv3;
      float4 a0 = *reinterpret_cast<const float4*>(&alpha[(size_t)(p + q) * 8]);
      float4 a1 = *reinterpret_cast<const float4*>(&alpha[(size_t)(p + q) * 8 + 4]);
      acc[0] += a0.x * xv; acc[1] += a0.y * xv;
      acc[2] += a0.z * xv; acc[3] += a0.w * xv;
      acc[4] += a1.x * xv; acc[5] += a1.y * xv;
      acc[6] += a1.z * xv; acc[7] += a1.w * xv;
    }
  }
  for (; p < r1; ++p) {
    int s0 = esrc[p];
    float xv = X[((unsigned)s0 << 6) + lane];
    float4 a0 = *reinterpret_cast<const float4*>(&alpha[(size_t)p * 8]);
    float4 a1 = *reinterpret_cast<const float4*>(&alpha[(size_t)p * 8 + 4]);
    acc[0] += a0.x * xv; acc[1] += a0.y * xv;
    acc[2] += a0.z * xv; acc[3] += a0.w * xv;
    acc[4] += a1.x * xv; acc[5] += a1.y * xv;
    acc[6] += a1.z * xv; acc[7] += a1.w * xv;
  }
  unsigned base = (unsigned)node * 512 + lane;
#pragma unroll
  for (int h = 0; h < 8; ++h) AGG[base + h * 64] = acc[h];
}

__global__ __launch_bounds__(256) void proj1(const float* __restrict__ AGG,
                                             const float* __restrict__ W1,
                                             const float* __restrict__ b1,
                                             float* __restrict__ OUT, int n) {
  int w = blockIdx.x * 4 + (threadIdx.x >> 6);
  int lane = threadIdx.x & 63;
  int node0 = w * 8;
  if (node0 >= n) return;
  int h = lane >> 3;
  float acc[8];
#pragma unroll
  for (int j = 0; j < 8; ++j) acc[j] = 0.f;
  for (int k = 0; k < 32; ++k) {
    float wv = W1[k * 64 + lane];
#pragma unroll
    for (int j = 0; j < 8; ++j) {
      int nd = min(node0 + j, n - 1);
      acc[j] += AGG[(unsigned)nd * 256 + h * 32 + k] * wv;
    }
  }
  float bv = b1[lane];
#pragma unroll
  for (int j = 0; j < 8; ++j) {
    int nd = node0 + j;
    if (nd >= n) break;
    float v = acc[j] + bv;
    v = v > 0.f ? v : expm1f(v);
    OUT[(unsigned)nd * 64 + lane] = v;
  }
}

__global__ __launch_bounds__(256) void proj2(const float* __restrict__ AGG,
                                             const float* __restrict__ W2,
                                             const float* __restrict__ b2,
                                             float* __restrict__ OUT, int n) {
  int w = blockIdx.x * 4 + (threadIdx.x >> 6);
  int lane = threadIdx.x & 63;
  int node0 = w * 4;
  if (node0 >= n) return;
  int c0 = lane * 8;
  int h = lane >> 3;
  float acc[4][8];
#pragma unroll
  for (int j = 0; j < 4; ++j)
#pragma unroll
    for (int c = 0; c < 8; ++c) acc[j][c] = 0.f;
  for (int k = 0; k < 64; ++k) {
    const float4 w0 = *reinterpret_cast<const float4*>(&W2[(size_t)k * 512 + c0]);
    const float4 w1 = *reinterpret_cast<const float4*>(&W2[(size_t)k * 512 + c0 + 4]);
#pragma unroll
    for (int j = 0; j < 4; ++j) {
      int nd = min(node0 + j, n - 1);
      float xv = AGG[(unsigned)nd * 512 + h * 64 + k];
      acc[j][0] += xv * w0.x; acc[j][1] += xv * w0.y;
      acc[j][2] += xv * w0.z; acc[j][3] += xv * w0.w;
      acc[j][4] += xv * w1.x; acc[j][5] += xv * w1.y;
      acc[j][6] += xv * w1.z; acc[j][7] += xv * w1.w;
    }
  }
  float4 bv0 = *reinterpret_cast<const float4*>(&b2[c0]);
  float4 bv1 = *reinterpret_cast<const float4*>(&b2[c0 + 4]);
#pragma unroll
  for (int j = 0; j < 4; ++j) {
    int nd = node0 + j;
    if (nd >= n) break;
    float v[8];
    v[0] = acc[j][0] + bv0.x; v[1] = acc[j][1] + bv0.y;
    v[2] = acc[j][2] + bv0.z; v[3] = acc[j][3] + bv0.w;
    v[4] = acc[j][4] + bv1.x; v[5] = acc[j][5] + bv1.y;
    v[6] = acc[j][6] + bv1.z; v[7] = acc[j][7] + bv1.w;
#pragma unroll
    for (int c = 0; c < 8; ++c) v[c] = v[c] > 0.f ? v[c] : expm1f(v[c]);
    float4* o = reinterpret_cast<float4*>(&OUT[(unsigned)nd * 512 + c0]);
    o[0] = make_float4(v[0], v[1], v[2], v[3]);
    o[1] = make_float4(v[4], v[5], v[6], v[7]);
  }
}

__global__ __launch_bounds__(256) void gemm_l3f(const float* __restrict__ X,
                                                const float* __restrict__ W,
                                                const float* __restrict__ As,
                                                const float* __restrict__ Ad,
                                                float* __restrict__ H,
                                                float* __restrict__ als,
                                                float* __restrict__ ald,
                                                float* __restrict__ selfe, int n) {
  int node = blockIdx.x * 4 + (threadIdx.x >> 6);
  int lane = threadIdx.x & 63;
  if (node >= n) return;
  float acc[6] = {0.f, 0.f, 0.f, 0.f, 0.f, 0.f};
  for (int k = lane; k < 512; k += 64) {
    float xv = X[(size_t)node * 512 + k];
#pragma unroll
    for (int c = 0; c < 6; ++c) acc[c] += xv * W[k * 6 + c];
  }
#pragma unroll
  for (int c = 0; c < 6; ++c) {
#pragma unroll
    for (int off = 32; off >= 1; off >>= 1)
      acc[c] += __shfl_down(acc[c], off, 64);
  }
  if (lane == 0) {
    float s0 = 0.f, s1 = 0.f;
#pragma unroll
    for (int c = 0; c < 6; ++c) {
      H[(size_t)node * 6 + c] = acc[c];
      s0 += acc[c] * As[c];
      s1 += acc[c] * Ad[c];
    }
    als[node] = s0;
    ald[node] = s1;
    selfe[node] = lrelu(s0 + s1);
  }
}

__global__ __launch_bounds__(256) void agg_l3(const float* __restrict__ HF,
                                              const float* __restrict__ alpha,
                                              const float* __restrict__ asel,
                                              const float* __restrict__ bias,
                                              const int* __restrict__ rowptr,
                                              const int* __restrict__ esrc,
                                              float* __restrict__ OUT, int n) {
  int node = blockIdx.x * 4 + (threadIdx.x >> 6);
  int lane = threadIdx.x & 63;
  if (node >= n) return;
  int ch = lane < 6 ? lane : 0;
  float acc = asel[node] * HF[(unsigned)node * 6u + ch];
  int r0 = rowptr[node], r1 = rowptr[node + 1];
  int p = r0;
  for (; p + 2 <= r1; p += 2) {
    int s0 = esrc[p], s1 = esrc[p + 1];
    float h0 = HF[(unsigned)s0 * 6u + ch];
    float h1 = HF[(unsigned)s1 * 6u + ch];
    acc += alpha[p] * h0 + alpha[p + 1] * h1;
  }
  if (p < r1) acc += alpha[p] * HF[(unsigned)esrc[p] * 6u + ch];
  if (lane < 6) OUT[(unsigned)node * 6u + lane] = acc + bias[lane];
}

// ---------------- launch ----------------

extern "C" void kernel_launch(void* const* d_in, const int* in_sizes, int n_in,
                              void* d_out, int out_size, void* d_ws, size_t ws_size,
                              hipStream_t stream) {
  const float* x     = (const float*)d_in[0];
  const int*   ei    = (const int*)d_in[1];
  const float* W1    = (const float*)d_in[2];
  const float* asrc1 = (const float*)d_in[3];
  const float* adst1 = (const float*)d_in[4];
  const float* b1    = (const float*)d_in[5];
  const float* W2    = (const float*)d_in[6];
  const float* asrc2 = (const float*)d_in[7];
  const float* adst2 = (const float*)d_in[8];
  const float* b2    = (const float*)d_in[9];
  const float* W3    = (const float*)d_in[10];
  const float* asrc3 = (const float*)d_in[11];
  const float* adst3 = (const float*)d_in[12];
  const float* b3    = (const float*)d_in[13];
  float* outf = (float*)d_out;

  const int n = in_sizes[0] / 32;   // 10000
  const int E = in_sizes[1] / 2;    // 160000

  char* ws = (char*)d_ws;
  size_t off = 0;
  auto alloc = [&](size_t bytes) {
    size_t o = off;
    off = (off + bytes + 255) & ~(size_t)255;
    return ws + o;
  };
  int* deg     = (int*)alloc((size_t)n * 4);
  int* rowptr  = (int*)alloc((size_t)(n + 1) * 4);
  int* cursor  = (int*)alloc((size_t)n * 4);
  int* esrc    = (int*)alloc((size_t)E * 4);
  float* alpha = (float*)alloc((size_t)E * 8 * 4);   // fallback only
  float* selfe = (float*)alloc((size_t)n * 8 * 4);
  float* als   = (float*)alloc((size_t)n * 8 * 4);
  float* ald   = (float*)alloc((size_t)n * 8 * 4);
  float* asel  = (float*)alloc((size_t)n * 8 * 4);   // fallback only
  float* av    = (float*)alloc((size_t)1536 * 4);
  float* AGG1  = (float*)alloc((size_t)n * 256 * 4); // fallback only
  float* x1    = (float*)alloc((size_t)n * 64 * 4);
  float* AGG2  = (float*)alloc((size_t)n * 512 * 4); // fallback only
  float* x2    = (float*)alloc((size_t)n * 512 * 4);
  float* h3    = (float*)alloc((size_t)n * 6 * 4);

  // ---- try the single cooperative kernel ----
  bool coop_done = false;
  {
    int dev = 0;
    (void)hipGetDevice(&dev);
    int cus = 0;
    (void)hipDeviceGetAttribute(&cus, hipDeviceAttributeMultiprocessorCount, dev);
    int nbpc = 0;
    hipError_t oe = hipOccupancyMaxActiveBlocksPerMultiprocessor(
        &nbpc, reinterpret_cast<const void*>(gat_coop), 256, 0);
    if (oe == hipSuccess && nbpc > 0 && cus > 0) {
      int gridsz = nbpc * cus;
      if (gridsz > 2048) gridsz = 2048;
      if (gridsz >= 8) {
        CoopP P;
        P.x = x; P.ei = ei;
        P.W1 = W1; P.as1 = asrc1; P.ad1 = adst1; P.b1 = b1;
        P.W2 = W2; P.as2 = asrc2; P.ad2 = adst2; P.b2 = b2;
        P.W3 = W3; P.as3 = asrc3; P.ad3 = adst3; P.b3 = b3;
        P.outf = outf; P.n = n; P.E = E;
        P.deg = deg; P.rowptr = rowptr; P.cursor = cursor; P.esrc = esrc;
        P.als = als; P.ald = ald; P.selfe = selfe; P.av = av;
        P.x1 = x1; P.x2 = x2; P.h3 = h3;
        void* args[] = { &P };
        hipError_t rc = hipLaunchCooperativeKernel(
            reinterpret_cast<const void*>(gat_coop), dim3(gridsz), dim3(256),
            args, 0, stream);
        if (rc == hipSuccess) coop_done = true;
        else (void)hipGetLastError();  // clear error state
      }
    } else {
      (void)hipGetLastError();
    }
  }

  if (!coop_done) {
    // ---- fallback: proven round-5 sequence ----
    int nb4 = (n + 3) / 4;
    hipMemsetAsync(deg, 0, (size_t)n * 4, stream);
    count_deg<<<(E + 255) / 256, 256, 0, stream>>>(ei, deg, E);
    scan3<<<3, 1024, 0, stream>>>(deg, rowptr, cursor, n,
                                  W1, asrc1, adst1, W2, asrc2, adst2, av);
    fill_edges<<<(E + 255) / 256, 256, 0, stream>>>(ei, cursor, esrc, E);

    logits_x<8, 32><<<(n * 8 + 255) / 256, 256, 0, stream>>>(x, av, av + 256, als, ald, selfe, n);
    msum_alpha8<<<nb4, 256, 0, stream>>>(esrc, als, ald, selfe, rowptr, alpha, asel, n);
    agg1<<<nb4, 256, 0, stream>>>(x, alpha, asel, rowptr, esrc, AGG1, n);
    proj1<<<(n / 8 + 3) / 4 + 1, 256, 0, stream>>>(AGG1, W1, b1, x1, n);

    logits_x<8, 64><<<(n * 8 + 255) / 256, 256, 0, stream>>>(x1, av + 512, av + 1024, als, ald, selfe, n);
    msum_alpha8<<<nb4, 256, 0, stream>>>(esrc, als, ald, selfe, rowptr, alpha, asel, n);
    agg2<<<nb4, 256, 0, stream>>>(x1, alpha, asel, rowptr, esrc, AGG2, n);
    proj2<<<(n / 4 + 3) / 4 + 1, 256, 0, stream>>>(AGG2, W2, b2, x2, n);

    gemm_l3f<<<nb4, 256, 0, stream>>>(x2, W3, asrc3, adst3, h3, als, ald, selfe, n);
    msum_alpha1<<<nb4, 256, 0, stream>>>(esrc, als, ald, selfe, rowptr, alpha, asel, n);
    agg_l3<<<nb4, 256, 0, stream>>>(h3, alpha, asel, b3, rowptr, esrc, outf, n);
  }
}